// Round 2
// baseline (7804.557 us; speedup 1.0000x reference)
//
#include <hip/hip_runtime.h>
#include <hip/hip_bf16.h>

#define BB 4
#define LL 2048
#define DD 256
#define VV 240
#define NLAYERS 6

static constexpr long BLD = (long)BB * LL * DD;   // 2,097,152
static constexpr long LD_ = (long)LL * DD;        // 524,288
static constexpr long LxL = (long)LL * LL;        // 4,194,304
static constexpr long BLL = (long)BB * LxL;       // 16,777,216

// ---------------- embedding + positional encoding ----------------
__global__ __launch_bounds__(256)
void embed_kernel(const int* __restrict__ tokens, const float* __restrict__ table,
                  float* __restrict__ x)
{
    long idx = (long)blockIdx.x * 256 + threadIdx.x;
    if (idx >= BLD) return;
    int i  = (int)(idx & (DD - 1));
    long bl = idx >> 8;                  // D = 256
    int l  = (int)(bl & (LL - 1));
    int tok = tokens[bl];
    float base = (float)l * 1e-5f;
    float p = powf(base, (float)i * (1.0f / (float)DD));   // powf(0,0)=1 matches numpy
    float ang = p - ((i & 1) ? 0.0f : 1.57079632679489662f); // even i: -pi/2
    x[idx] = table[(long)tok * DD + i] + sinf(ang);
}

// ---------------- elementwise: k -= q  (E = K - Q) ----------------
__global__ __launch_bounds__(256)
void sub_kernel(float* __restrict__ kk, const float* __restrict__ q, int n)
{
    int i = blockIdx.x * 256 + threadIdx.x;
    if (i < n) kk[i] -= q[i];
}

// ---------------- generic f32 tiled GEMM ----------------
// C[M,N] = A[M,K] * B   with B = [K,N] (BT=false) or B = [N,K] used transposed (BT=true)
// EPI bits: 1 = +bias[n], 2 = leaky_relu(0.2), 4 = +Cadd (residual)
// batching via blockIdx.z with strides sA,sB,sC
template<bool BT, int EPI>
__global__ __launch_bounds__(256)
void gemm_f32(const float* __restrict__ A, const float* __restrict__ Bm,
              const float* __restrict__ Cadd, const float* __restrict__ bias,
              float* __restrict__ C, int M, int N, int K,
              long sA, long sB, long sC)
{
    constexpr int BM = 128, BN = 128, BK = 16;
    __shared__ float As[BK][BM + 4];
    __shared__ float Bs[BK][BN + 4];
    const int bz = blockIdx.z;
    A  += (long)bz * sA;
    Bm += (long)bz * sB;
    C  += (long)bz * sC;
    const float* Ca = nullptr;
    if (EPI & 4) Ca = Cadd + (long)bz * sC;
    const int bm = blockIdx.y * BM;
    const int bn = blockIdx.x * BN;
    const int tid = threadIdx.x;
    const int tx = tid & 15, ty = tid >> 4;

    float acc[8][8];
    #pragma unroll
    for (int i = 0; i < 8; ++i) {
        #pragma unroll
        for (int j = 0; j < 8; ++j) acc[i][j] = 0.f;
    }

    for (int k0 = 0; k0 < K; k0 += BK) {
        // ---- stage A tile (BM x BK), transposed into As[k][m]
        #pragma unroll
        for (int u = 0; u < 2; ++u) {
            int qi = tid + u * 256;          // float4 id, 512 total
            int row = qi >> 2;
            int c4  = (qi & 3) * 4;
            float4 f = *(const float4*)&A[(long)(bm + row) * K + k0 + c4];
            As[c4 + 0][row] = f.x; As[c4 + 1][row] = f.y;
            As[c4 + 2][row] = f.z; As[c4 + 3][row] = f.w;
        }
        // ---- stage B tile into Bs[k][n]
        if constexpr (BT) {
            #pragma unroll
            for (int u = 0; u < 2; ++u) {
                int qi = tid + u * 256;
                int row = qi >> 2;           // n-index
                int c4  = (qi & 3) * 4;      // k-offset
                float4 f = *(const float4*)&Bm[(long)(bn + row) * K + k0 + c4];
                Bs[c4 + 0][row] = f.x; Bs[c4 + 1][row] = f.y;
                Bs[c4 + 2][row] = f.z; Bs[c4 + 3][row] = f.w;
            }
        } else {
            #pragma unroll
            for (int u = 0; u < 2; ++u) {
                int qi = tid + u * 256;
                int row = qi >> 5;           // k-index (32 float4 per row)
                int c4  = (qi & 31) * 4;     // n-offset
                float4 f = *(const float4*)&Bm[(long)(k0 + row) * N + bn + c4];
                *(float4*)&Bs[row][c4] = f;
            }
        }
        __syncthreads();
        #pragma unroll
        for (int kk = 0; kk < BK; ++kk) {
            float a[8], b[8];
            *(float4*)&a[0] = *(const float4*)&As[kk][ty * 8];
            *(float4*)&a[4] = *(const float4*)&As[kk][ty * 8 + 4];
            *(float4*)&b[0] = *(const float4*)&Bs[kk][tx * 8];
            *(float4*)&b[4] = *(const float4*)&Bs[kk][tx * 8 + 4];
            #pragma unroll
            for (int i = 0; i < 8; ++i) {
                #pragma unroll
                for (int j = 0; j < 8; ++j)
                    acc[i][j] = fmaf(a[i], b[j], acc[i][j]);
            }
        }
        __syncthreads();
    }

    // ---- epilogue
    #pragma unroll
    for (int i = 0; i < 8; ++i) {
        long r = bm + ty * 8 + i;
        float* crow = C + r * N + bn + tx * 8;
        float vs[8];
        #pragma unroll
        for (int j = 0; j < 8; ++j) {
            float t = acc[i][j];
            if (EPI & 1) t += bias[bn + tx * 8 + j];
            if (EPI & 2) t = (t >= 0.f) ? t : 0.2f * t;
            vs[j] = t;
        }
        if (EPI & 4) {
            const float* arow = Ca + r * N + bn + tx * 8;
            float4 r0 = *(const float4*)&arow[0];
            float4 r1 = *(const float4*)&arow[4];
            vs[0] += r0.x; vs[1] += r0.y; vs[2] += r0.z; vs[3] += r0.w;
            vs[4] += r1.x; vs[5] += r1.y; vs[6] += r1.z; vs[7] += r1.w;
        }
        *(float4*)&crow[0] = make_float4(vs[0], vs[1], vs[2], vs[3]);
        *(float4*)&crow[4] = make_float4(vs[4], vs[5], vs[6], vs[7]);
    }
}

// ---------------- skew + scale + softmax (in-place on S1) ----------------
// scores[b,i,m] = (S1[b,i,m] + Srel[b,i,m]) / 8 ; probs = softmax_m
// Srel[i,m] = QE[i, m-i+L-1]   (m <= i)
//           = 0                (m == i+1)
//           = QE[i+1, m-i-2]   (m >= i+2)
__global__ __launch_bounds__(256)
void skew_softmax(float* __restrict__ S1, const float* __restrict__ QE)
{
    const int bi = blockIdx.x;         // b*L + i
    const int b = bi >> 11;
    const int i = bi & (LL - 1);
    float* srow = S1 + (long)bi * LL;
    const float* qe_i  = QE + ((long)b * LL + i) * LL;
    const int i1 = (i + 1 < LL) ? (i + 1) : i;   // i+1 branch unreachable when i==L-1
    const float* qe_i1 = QE + ((long)b * LL + i1) * LL;
    const int t = threadIdx.x;

    float vals[8];
    float mx = -1e30f;
    #pragma unroll
    for (int j = 0; j < 8; ++j) {
        int m = t + j * 256;
        float srel;
        if (m <= i)            srel = qe_i[m - i + (LL - 1)];
        else if (m == i + 1)   srel = 0.f;
        else                   srel = qe_i1[m - i - 2];
        float s = (srow[m] + srel) * 0.125f;   // /sqrt(64)
        vals[j] = s;
        mx = fmaxf(mx, s);
    }
    #pragma unroll
    for (int off = 32; off >= 1; off >>= 1)
        mx = fmaxf(mx, __shfl_xor(mx, off, 64));
    __shared__ float redm[4], reds[4];
    const int wid = t >> 6;
    if ((t & 63) == 0) redm[wid] = mx;
    __syncthreads();
    mx = fmaxf(fmaxf(redm[0], redm[1]), fmaxf(redm[2], redm[3]));

    float sum = 0.f;
    #pragma unroll
    for (int j = 0; j < 8; ++j) { vals[j] = expf(vals[j] - mx); sum += vals[j]; }
    #pragma unroll
    for (int off = 32; off >= 1; off >>= 1)
        sum += __shfl_xor(sum, off, 64);
    if ((t & 63) == 0) reds[wid] = sum;
    __syncthreads();
    sum = reds[0] + reds[1] + reds[2] + reds[3];
    float inv = 1.0f / sum;
    #pragma unroll
    for (int j = 0; j < 8; ++j) srow[t + j * 256] = vals[j] * inv;
}

// ---------------- final classifier ----------------
// stage 1: 256 blocks, each reduces a 2048-feature chunk for all (b,v)
__global__ __launch_bounds__(960)
void fc_partial(const float* __restrict__ x, const float* __restrict__ W,
                float* __restrict__ part)
{
    const int v = threadIdx.x;       // 0..239
    const int b = threadIdx.y;       // 0..3
    const int chunk = blockIdx.x;    // 0..255
    const int KC = (int)(LD_ / 256); // 2048
    const long k0 = (long)chunk * KC;
    const float* xb = x + (long)b * LD_ + k0;
    const float* Wp = W + k0 * VV + v;
    float acc = 0.f;
    #pragma unroll 4
    for (int k2 = 0; k2 < KC; ++k2)
        acc = fmaf(xb[k2], Wp[(long)k2 * VV], acc);
    part[((long)chunk * BB + b) * VV + v] = acc;
}

// stage 2: reduce partials, +bias, softmax over vocab, write f32
__global__ __launch_bounds__(960)
void fc_finish(const float* __restrict__ part, const float* __restrict__ bias,
               float* __restrict__ out)
{
    const int v = threadIdx.x, b = threadIdx.y;
    float acc = bias[v];
    for (int c = 0; c < 256; ++c)
        acc += part[((long)c * BB + b) * VV + v];
    __shared__ float lds[BB][VV];
    __shared__ float mxs[BB], sms[BB];
    lds[b][v] = acc;
    __syncthreads();
    if (v == 0) {
        float m = -1e30f;
        for (int j = 0; j < VV; ++j) m = fmaxf(m, lds[b][j]);
        float s = 0.f;
        for (int j = 0; j < VV; ++j) s += expf(lds[b][j] - m);
        mxs[b] = m; sms[b] = s;
    }
    __syncthreads();
    float p = expf(lds[b][v] - mxs[b]) / sms[b];
    out[b * VV + v] = p;   // reference output dtype is float32
}

// ---------------- driver ----------------
extern "C" void kernel_launch(void* const* d_in, const int* in_sizes, int n_in,
                              void* d_out, int out_size, void* d_ws, size_t ws_size,
                              hipStream_t stream)
{
    const int*   tokens = (const int*)d_in[0];
    const float* table  = (const float*)d_in[1];
    const float* Wq1 = (const float*)d_in[2];
    const float* Wk1 = (const float*)d_in[3];
    const float* Wv1 = (const float*)d_in[4];
    const float* Wq2 = (const float*)d_in[5];
    const float* Wk2 = (const float*)d_in[6];
    const float* Wv2 = (const float*)d_in[7];
    const float* Wf1 = (const float*)d_in[8];
    const float* bf1 = (const float*)d_in[9];
    const float* Wf2 = (const float*)d_in[10];
    const float* bf2 = (const float*)d_in[11];
    const float* Wfc = (const float*)d_in[12];
    const float* bfc = (const float*)d_in[13];

    float* ws = (float*)d_ws;
    float* x    = ws;                 // [B,L,D]
    float* q    = x + BLD;            // [B,L,D]  (reused as FFN hidden h)
    float* kk   = q + BLD;            // [B,L,D]  (becomes E = K-Q in place)
    float* vv   = kk + BLD;           // [B,L,D]
    float* S1   = vv + BLD;           // [B,L,L]  (QK^T, then probs in place)
    float* QE   = S1 + BLL;           // [B,L,L]
    float* part = QE + BLL;           // [256,B,V]

    embed_kernel<<<(int)((BLD + 255) / 256), 256, 0, stream>>>(tokens, table, x);

    const dim3 gproj(DD / 128, (BB * LL) / 128, 1);  // [8192,256] gemms
    const dim3 gscore(LL / 128, LL / 128, BB);       // [2048,2048] gemms
    const dim3 gpv(DD / 128, LL / 128, BB);          // [2048,256]  gemms

    for (int layer = 0; layer < NLAYERS; ++layer) {
        for (int half = 0; half < 2; ++half) {
            const float* Wq = (half ? Wq2 : Wq1) + (long)layer * DD * DD;
            const float* Wk = (half ? Wk2 : Wk1) + (long)layer * DD * DD;
            const float* Wv = (half ? Wv2 : Wv1) + (long)layer * DD * DD;
            // projections
            gemm_f32<false, 0><<<gproj, 256, 0, stream>>>(x, Wq, nullptr, nullptr, q,
                                                          BB * LL, DD, DD, 0, 0, 0);
            gemm_f32<false, 0><<<gproj, 256, 0, stream>>>(x, Wk, nullptr, nullptr, kk,
                                                          BB * LL, DD, DD, 0, 0, 0);
            gemm_f32<false, 0><<<gproj, 256, 0, stream>>>(x, Wv, nullptr, nullptr, vv,
                                                          BB * LL, DD, DD, 0, 0, 0);
            // S1 = Q K^T (batched)
            gemm_f32<true, 0><<<gscore, 256, 0, stream>>>(q, kk, nullptr, nullptr, S1,
                                                          LL, LL, DD, LD_, LD_, LxL);
            // E = K - Q (in place on kk)
            sub_kernel<<<(int)((BLD + 255) / 256), 256, 0, stream>>>(kk, q, (int)BLD);
            // QE = Q E^T (batched)
            gemm_f32<true, 0><<<gscore, 256, 0, stream>>>(q, kk, nullptr, nullptr, QE,
                                                          LL, LL, DD, LD_, LD_, LxL);
            // probs = softmax((S1 + skew(QE))/8), in place on S1
            skew_softmax<<<BB * LL, 256, 0, stream>>>(S1, QE);
            // x = probs @ V + x (batched, residual)
            gemm_f32<false, 4><<<gpv, 256, 0, stream>>>(S1, vv, x, nullptr, x,
                                                        LL, DD, LL, LxL, LD_, LD_);
        }
        // FFN (no residual per reference)
        const float* wf1 = Wf1 + (long)layer * DD * DD;
        const float* wf2 = Wf2 + (long)layer * DD * DD;
        gemm_f32<false, 3><<<gproj, 256, 0, stream>>>(x, wf1, nullptr, bf1 + layer * DD, q,
                                                      BB * LL, DD, DD, 0, 0, 0);
        gemm_f32<false, 1><<<gproj, 256, 0, stream>>>(q, wf2, nullptr, bf2 + layer * DD, x,
                                                      BB * LL, DD, DD, 0, 0, 0);
    }

    fc_partial<<<256, dim3(VV, BB, 1), 0, stream>>>(x, Wfc, part);
    fc_finish<<<1, dim3(VV, BB, 1), 0, stream>>>(part, bfc, (float*)d_out);
}

// Round 3
// 2351.488 us; speedup vs baseline: 3.3190x; 3.3190x over previous
//
#include <hip/hip_runtime.h>

typedef unsigned short u16;
typedef unsigned int   u32;

#define BB 4
#define LL 2048
#define DD 256
#define VV 240
#define NLAYERS 6

static constexpr long BLD = (long)BB * LL * DD;   // 2,097,152
static constexpr long LD_ = (long)LL * DD;        // 524,288
static constexpr long LxL = (long)LL * LL;        // 4,194,304
static constexpr long BLL = (long)BB * LxL;       // 16,777,216

typedef short s16x8 __attribute__((ext_vector_type(8)));   // 8 bf16 (4 VGPRs)
typedef float f32x4 __attribute__((ext_vector_type(4)));

__device__ __forceinline__ u16 f2b(float f) {              // f32 -> bf16 bits, RNE
    u32 u = __float_as_uint(f);
    u = (u + 0x7FFFu + ((u >> 16) & 1u)) >> 16;
    return (u16)u;
}
__device__ __forceinline__ float b2f(u16 h) { return __uint_as_float(((u32)h) << 16); }

__device__ __forceinline__ void gl16(const void* g, void* l) {
    __builtin_amdgcn_global_load_lds((const __attribute__((address_space(1))) void*)g,
                                     (__attribute__((address_space(3))) void*)l, 16, 0, 0);
}

// ---------------- embedding + positional encoding (writes f32 x and bf16 xh) ----------------
__global__ __launch_bounds__(256)
void embed_kernel(const int* __restrict__ tokens, const float* __restrict__ table,
                  float* __restrict__ x, u16* __restrict__ xh)
{
    long idx = (long)blockIdx.x * 256 + threadIdx.x;
    if (idx >= BLD) return;
    int i  = (int)(idx & (DD - 1));
    long bl = idx >> 8;
    int l  = (int)(bl & (LL - 1));
    int tok = tokens[bl];
    float base = (float)l * 1e-5f;
    float p = powf(base, (float)i * (1.0f / (float)DD));
    float ang = p - ((i & 1) ? 0.0f : 1.57079632679489662f);
    float v = table[(long)tok * DD + i] + sinf(ang);
    x[idx] = v;
    xh[idx] = f2b(v);
}

// ---------------- weight convert + transpose: Wt[n][k] = bf16(W[k][n]) ----------------
__global__ __launch_bounds__(256)
void wconv(const float* __restrict__ W, u16* __restrict__ Wt)
{
    int blk = blockIdx.x;            // nmat*64 blocks, 32x32 tiles
    int m  = blk >> 6;
    int ti = (blk >> 3) & 7;         // k tile
    int tj = blk & 7;                // n tile
    const float* src = W + (long)m * 65536;
    u16* dst = Wt + (long)m * 65536;
    __shared__ float tile[32][33];
    int t = threadIdx.x;
    int c = t & 31, r8 = t >> 5;
    #pragma unroll
    for (int p = 0; p < 4; ++p) {
        int r = r8 + p * 8;
        tile[r][c] = src[(long)(ti * 32 + r) * 256 + tj * 32 + c];
    }
    __syncthreads();
    #pragma unroll
    for (int p = 0; p < 4; ++p) {
        int n = r8 + p * 8;
        dst[(long)(tj * 32 + n) * 256 + ti * 32 + c] = f2b(tile[c][n]);
    }
}

// ---------------- E = K - Q (bf16, vectorized) ----------------
__global__ __launch_bounds__(256)
void sub_bf16(u16* __restrict__ kk, const u16* __restrict__ q)
{
    long i = (long)blockIdx.x * 256 + threadIdx.x;   // uint4 index
    if (i >= BLD / 8) return;
    uint4 kv = ((const uint4*)kk)[i];
    uint4 qv = ((const uint4*)q)[i];
    u32* kp = (u32*)&kv; const u32* qp = (const u32*)&qv;
    #pragma unroll
    for (int j = 0; j < 4; ++j) {
        u32 a = kp[j], b = qp[j];
        u16 lo = f2b(b2f((u16)(a & 0xffff)) - b2f((u16)(b & 0xffff)));
        u16 hi = f2b(b2f((u16)(a >> 16))   - b2f((u16)(b >> 16)));
        kp[j] = (u32)lo | ((u32)hi << 16);
    }
    ((uint4*)kk)[i] = kv;
}

// ---------------- bf16 MFMA GEMM: C[M,N] = A[M,K] (ldA) * B^T  (B stored [N][K], pitch K) ----
// EPI bits: 1=+bias[n](f32)  2=leaky(0.2)  4=+Cres(f32)  8=write Cf(f32)
//           16=write Ch(bf16, row-major)   32=write Ch transposed as [b][n][m] (V^T)
template<int EPI>
__global__ __launch_bounds__(256)
void gemm_mfma(const u16* __restrict__ A, const u16* __restrict__ B,
               const float* __restrict__ bias, const float* __restrict__ Cres,
               float* __restrict__ Cf, u16* __restrict__ Ch,
               int M, int N, int K, int ldA,
               long sA, long sB, long sC)
{
    __shared__ u16 As[128 * 32];
    __shared__ u16 Bs[128 * 32];
    const int bz = blockIdx.z;
    A += (long)bz * sA;
    B += (long)bz * sB;
    if constexpr (EPI & 4)  Cres += (long)bz * sC;
    if constexpr (EPI & 8)  Cf   += (long)bz * sC;
    if constexpr ((EPI & 16) && !(EPI & 32)) Ch += (long)bz * sC;
    const int bm = blockIdx.y * 128;
    const int bn = blockIdx.x * 128;
    const int t = threadIdx.x;
    const int lane = t & 63, wave = t >> 6;
    const int wm = (wave >> 1) * 64, wn = (wave & 1) * 64;

    f32x4 acc[4][4];
    #pragma unroll
    for (int i = 0; i < 4; ++i)
        #pragma unroll
        for (int j = 0; j < 4; ++j)
            acc[i][j] = (f32x4){0.f, 0.f, 0.f, 0.f};

    const u16* gA0 = A + (long)(bm + (t >> 2)) * ldA + (t & 3) * 8;
    const u16* gA1 = gA0 + 64L * ldA;
    const u16* gB0 = B + (long)(bn + (t >> 2)) * K + (t & 3) * 8;
    const u16* gB1 = gB0 + 64L * K;
    u16* lA0 = As + wave * 512;          // wave-uniform LDS bases
    u16* lA1 = As + 2048 + wave * 512;
    u16* lB0 = Bs + wave * 512;
    u16* lB1 = Bs + 2048 + wave * 512;

    const int ar = wm + (lane & 15);
    const int br = wn + (lane & 15);
    const int ko = (lane >> 4) * 8;

    for (int k0 = 0; k0 < K; k0 += 32) {
        __syncthreads();                 // previous tile fully consumed
        gl16(gA0, lA0); gl16(gA1, lA1);
        gl16(gB0, lB0); gl16(gB1, lB1);
        gA0 += 32; gA1 += 32; gB0 += 32; gB1 += 32;
        __syncthreads();                 // vmcnt(0) drained -> tile ready
        s16x8 af[4], bf[4];
        #pragma unroll
        for (int i = 0; i < 4; ++i) af[i] = *(const s16x8*)&As[(ar + i * 16) * 32 + ko];
        #pragma unroll
        for (int j = 0; j < 4; ++j) bf[j] = *(const s16x8*)&Bs[(br + j * 16) * 32 + ko];
        #pragma unroll
        for (int i = 0; i < 4; ++i)
            #pragma unroll
            for (int j = 0; j < 4; ++j)
                acc[i][j] = __builtin_amdgcn_mfma_f32_16x16x32_bf16(af[i], bf[j], acc[i][j], 0, 0, 0);
    }

    // epilogue: C/D layout col=lane&15, row=(lane>>4)*4+reg
    const int colc = lane & 15;
    const int rowb = (lane >> 4) * 4;
    if constexpr (EPI & 32) {
        #pragma unroll
        for (int i = 0; i < 4; ++i) {
            int r0 = bm + wm + i * 16 + rowb;
            int b  = r0 >> 11;            // batch (L = 2048)
            int m0 = r0 & (LL - 1);
            #pragma unroll
            for (int j = 0; j < 4; ++j) {
                int n = bn + wn + j * 16 + colc;
                f32x4 v = acc[i][j];
                ushort4 pk;
                pk.x = f2b(v.x); pk.y = f2b(v.y); pk.z = f2b(v.z); pk.w = f2b(v.w);
                *(ushort4*)&Ch[((long)b * DD + n) * LL + m0] = pk;
            }
        }
    } else {
        #pragma unroll
        for (int i = 0; i < 4; ++i) {
            #pragma unroll
            for (int j = 0; j < 4; ++j) {
                int n = bn + wn + j * 16 + colc;
                float bv = (EPI & 1) ? bias[n] : 0.f;
                #pragma unroll
                for (int r = 0; r < 4; ++r) {
                    long row = bm + wm + i * 16 + rowb + r;
                    float val = acc[i][j][r] + bv;
                    if (EPI & 2) val = (val >= 0.f) ? val : 0.2f * val;
                    long off = row * (long)N + n;
                    if (EPI & 4) val += Cres[off];
                    if (EPI & 8) Cf[off] = val;
                    if (EPI & 16) Ch[off] = f2b(val);
                }
            }
        }
    }
}

// ---------------- skew + scale + softmax; f32 in, bf16 probs in place --------
__global__ __launch_bounds__(256)
void skew_softmax(float* __restrict__ S1, const float* __restrict__ QE)
{
    const int bi = blockIdx.x;
    const int b = bi >> 11;
    const int i = bi & (LL - 1);
    float* srow = S1 + (long)bi * LL;
    const float* qe_i  = QE + ((long)b * LL + i) * LL;
    const int i1 = (i + 1 < LL) ? (i + 1) : i;
    const float* qe_i1 = QE + ((long)b * LL + i1) * LL;
    const int t = threadIdx.x;

    float vals[8];
    float mx = -1e30f;
    #pragma unroll
    for (int j = 0; j < 8; ++j) {
        int m = t + j * 256;
        float srel;
        if (m <= i)            srel = qe_i[m - i + (LL - 1)];
        else if (m == i + 1)   srel = 0.f;
        else                   srel = qe_i1[m - i - 2];
        float s = (srow[m] + srel) * 0.125f;
        vals[j] = s;
        mx = fmaxf(mx, s);
    }
    #pragma unroll
    for (int off = 32; off >= 1; off >>= 1)
        mx = fmaxf(mx, __shfl_xor(mx, off, 64));
    __shared__ float redm[4], reds[4];
    const int wid = t >> 6;
    if ((t & 63) == 0) redm[wid] = mx;
    __syncthreads();
    mx = fmaxf(fmaxf(redm[0], redm[1]), fmaxf(redm[2], redm[3]));

    float sum = 0.f;
    #pragma unroll
    for (int j = 0; j < 8; ++j) { vals[j] = expf(vals[j] - mx); sum += vals[j]; }
    #pragma unroll
    for (int off = 32; off >= 1; off >>= 1)
        sum += __shfl_xor(sum, off, 64);
    if ((t & 63) == 0) reds[wid] = sum;
    __syncthreads();               // all S1 reads complete before in-place bf16 writes
    sum = reds[0] + reds[1] + reds[2] + reds[3];
    float inv = 1.0f / sum;
    u16* prow = (u16*)srow;        // probs row, pitch 2*LL u16
    #pragma unroll
    for (int j = 0; j < 8; ++j) prow[t + j * 256] = f2b(vals[j] * inv);
}

// ---------------- final classifier ----------------
__global__ __launch_bounds__(960)
void fc_partial(const float* __restrict__ x, const float* __restrict__ W,
                float* __restrict__ part)
{
    const int v = threadIdx.x;
    const int b = threadIdx.y;
    const int chunk = blockIdx.x;
    const int KC = (int)(LD_ / 256);
    const long k0 = (long)chunk * KC;
    const float* xb = x + (long)b * LD_ + k0;
    const float* Wp = W + k0 * VV + v;
    float acc = 0.f;
    #pragma unroll 4
    for (int k2 = 0; k2 < KC; ++k2)
        acc = fmaf(xb[k2], Wp[(long)k2 * VV], acc);
    part[((long)chunk * BB + b) * VV + v] = acc;
}

__global__ __launch_bounds__(960)
void fc_finish(const float* __restrict__ part, const float* __restrict__ bias,
               float* __restrict__ out)
{
    const int v = threadIdx.x, b = threadIdx.y;
    float acc = bias[v];
    for (int c = 0; c < 256; ++c)
        acc += part[((long)c * BB + b) * VV + v];
    __shared__ float lds[BB][VV];
    __shared__ float mxs[BB], sms[BB];
    lds[b][v] = acc;
    __syncthreads();
    if (v == 0) {
        float m = -1e30f;
        for (int j = 0; j < VV; ++j) m = fmaxf(m, lds[b][j]);
        float s = 0.f;
        for (int j = 0; j < VV; ++j) s += expf(lds[b][j] - m);
        mxs[b] = m; sms[b] = s;
    }
    __syncthreads();
    out[b * VV + v] = expf(lds[b][v] - mxs[b]) / sms[b];
}

// ---------------- driver ----------------
extern "C" void kernel_launch(void* const* d_in, const int* in_sizes, int n_in,
                              void* d_out, int out_size, void* d_ws, size_t ws_size,
                              hipStream_t stream)
{
    const int*   tokens = (const int*)d_in[0];
    const float* table  = (const float*)d_in[1];
    const float* Wsrc[8] = { (const float*)d_in[2], (const float*)d_in[3],
                             (const float*)d_in[4], (const float*)d_in[5],
                             (const float*)d_in[6], (const float*)d_in[7],
                             (const float*)d_in[8], (const float*)d_in[10] }; // q1,k1,v1,q2,k2,v2,f1,f2
    const float* bf1 = (const float*)d_in[9];
    const float* bf2 = (const float*)d_in[11];
    const float* Wfc = (const float*)d_in[12];
    const float* bfc = (const float*)d_in[13];

    char* p = (char*)d_ws;
    float* x  = (float*)p; p += BLD * 4;
    u16* xh = (u16*)p;     p += BLD * 2;
    u16* qb = (u16*)p;     p += BLD * 2;
    u16* kb = (u16*)p;     p += BLD * 2;
    u16* vt = (u16*)p;     p += BLD * 2;      // [B][D][L]
    float* S1 = (float*)p; p += BLL * 4;      // scores, then bf16 probs in place
    float* QE = (float*)p; p += BLL * 4;
    u16* wt = (u16*)p;     p += 8L * 6 * 65536 * 2;
    float* part = (float*)p;
    u16* hb = qb;                             // FFN hidden aliases Q buffer

    for (int g = 0; g < 8; ++g)
        wconv<<<384, 256, 0, stream>>>(Wsrc[g], wt + (long)g * 6 * 65536);

    embed_kernel<<<(int)((BLD + 255) / 256), 256, 0, stream>>>(tokens, table, x, xh);

    const dim3 gproj(2, 64, 1);
    const dim3 gscore(16, 16, BB);
    const dim3 gpv(2, 16, BB);

    for (int layer = 0; layer < NLAYERS; ++layer) {
        for (int half = 0; half < 2; ++half) {
            const u16* wtq = wt + ((long)((half ? 3 : 0) * 6 + layer)) * 65536;
            const u16* wtk = wt + ((long)((half ? 4 : 1) * 6 + layer)) * 65536;
            const u16* wtv = wt + ((long)((half ? 5 : 2) * 6 + layer)) * 65536;
            gemm_mfma<16><<<gproj, 256, 0, stream>>>(xh, wtq, nullptr, nullptr, nullptr, qb,
                                                     BB * LL, DD, DD, DD, 0, 0, 0);
            gemm_mfma<16><<<gproj, 256, 0, stream>>>(xh, wtk, nullptr, nullptr, nullptr, kb,
                                                     BB * LL, DD, DD, DD, 0, 0, 0);
            gemm_mfma<32><<<gproj, 256, 0, stream>>>(xh, wtv, nullptr, nullptr, nullptr, vt,
                                                     BB * LL, DD, DD, DD, 0, 0, 0);
            gemm_mfma<8><<<gscore, 256, 0, stream>>>(qb, kb, nullptr, nullptr, S1, nullptr,
                                                     LL, LL, DD, DD, LD_, LD_, LxL);
            sub_bf16<<<(int)(BLD / 8 / 256), 256, 0, stream>>>(kb, qb);
            gemm_mfma<8><<<gscore, 256, 0, stream>>>(qb, kb, nullptr, nullptr, QE, nullptr,
                                                     LL, LL, DD, DD, LD_, LD_, LxL);
            skew_softmax<<<BB * LL, 256, 0, stream>>>(S1, QE);
            gemm_mfma<4 | 8 | 16><<<gpv, 256, 0, stream>>>((const u16*)S1, vt, nullptr, x, x, xh,
                                                           LL, DD, LL, 2 * LL, 2 * LxL, LD_, LD_);
        }
        const u16* wtf1 = wt + ((long)(6 * 6 + layer)) * 65536;
        const u16* wtf2 = wt + ((long)(7 * 6 + layer)) * 65536;
        gemm_mfma<1 | 2 | 16><<<gproj, 256, 0, stream>>>(xh, wtf1, bf1 + layer * DD, nullptr,
                                                         nullptr, hb, BB * LL, DD, DD, DD, 0, 0, 0);
        gemm_mfma<1 | 8 | 16><<<gproj, 256, 0, stream>>>(hb, wtf2, bf2 + layer * DD, nullptr,
                                                         x, xh, BB * LL, DD, DD, DD, 0, 0, 0);
    }

    fc_partial<<<256, dim3(VV, BB, 1), 0, stream>>>(x, Wfc, part);
    fc_finish<<<1, dim3(VV, BB, 1), 0, stream>>>(part, bfc, (float*)d_out);
}

// Round 4
// 1911.699 us; speedup vs baseline: 4.0825x; 1.2301x over previous
//
#include <hip/hip_runtime.h>
#include <hip/hip_fp16.h>

typedef unsigned short u16;
typedef unsigned int   u32;

#define BB 4
#define LL 2048
#define DD 256
#define VV 240
#define NLAYERS 6

static constexpr long BLD = (long)BB * LL * DD;   // 2,097,152
static constexpr long LD_ = (long)LL * DD;        // 524,288
static constexpr long LxL = (long)LL * LL;        // 4,194,304
static constexpr long BLL = (long)BB * LxL;       // 16,777,216

typedef _Float16 h8  __attribute__((ext_vector_type(8)));   // MFMA A/B fragment
typedef _Float16 h2v __attribute__((ext_vector_type(2)));
typedef float  f32x4 __attribute__((ext_vector_type(4)));

__device__ __forceinline__ u16 f2h(float f) {
    _Float16 h = (_Float16)f;
    return __builtin_bit_cast(u16, h);
}
__device__ __forceinline__ float h2f(u16 u) {
    return (float)__builtin_bit_cast(_Float16, u);
}

__device__ __forceinline__ void gl16(const void* g, void* l) {
    __builtin_amdgcn_global_load_lds((const __attribute__((address_space(1))) void*)g,
                                     (__attribute__((address_space(3))) void*)l, 16, 0, 0);
}

// ---------------- embedding + positional encoding ----------------
__global__ __launch_bounds__(256)
void embed_kernel(const int* __restrict__ tokens, const float* __restrict__ table,
                  float* __restrict__ x, u16* __restrict__ xh)
{
    long idx = (long)blockIdx.x * 256 + threadIdx.x;
    if (idx >= BLD) return;
    int i  = (int)(idx & (DD - 1));
    long bl = idx >> 8;
    int l  = (int)(bl & (LL - 1));
    int tok = tokens[bl];
    float base = (float)l * 1e-5f;
    float p = powf(base, (float)i * (1.0f / (float)DD));
    float ang = p - ((i & 1) ? 0.0f : 1.57079632679489662f);
    float v = table[(long)tok * DD + i] + sinf(ang);
    x[idx] = v;
    xh[idx] = f2h(v);
}

// ---------------- weight convert+transpose: dst[l*lstride + n*256 + k] = f16(W[l][k][n]) ----
__global__ __launch_bounds__(256)
void wconv(const float* __restrict__ W, u16* __restrict__ Wt, long lstride)
{
    int blk = blockIdx.x;            // 6 layers * 64 tiles
    int m  = blk >> 6;
    int ti = (blk >> 3) & 7;         // k tile
    int tj = blk & 7;                // n tile
    const float* src = W + (long)m * 65536;
    u16* dst = Wt + (long)m * lstride;
    __shared__ float tile[32][33];
    int t = threadIdx.x;
    int c = t & 31, r8 = t >> 5;
    #pragma unroll
    for (int p = 0; p < 4; ++p) {
        int r = r8 + p * 8;
        tile[r][c] = src[(long)(ti * 32 + r) * 256 + tj * 32 + c];
    }
    __syncthreads();
    #pragma unroll
    for (int p = 0; p < 4; ++p) {
        int n = r8 + p * 8;
        dst[(long)(tj * 32 + n) * 256 + ti * 32 + c] = f2h(tile[c][n]);
    }
}

// ---------------- E = K - Q (f16, vectorized) ----------------
__global__ __launch_bounds__(256)
void sub_f16(u16* __restrict__ kk, const u16* __restrict__ q)
{
    long i = (long)blockIdx.x * 256 + threadIdx.x;   // uint4 index (8 halves)
    uint4 kv = ((const uint4*)kk)[i];
    uint4 qv = ((const uint4*)q)[i];
    u32* kp = (u32*)&kv; const u32* qp = (const u32*)&qv;
    #pragma unroll
    for (int j = 0; j < 4; ++j) {
        h2v a = __builtin_bit_cast(h2v, kp[j]);
        h2v b = __builtin_bit_cast(h2v, qp[j]);
        h2v e = a - b;
        kp[j] = __builtin_bit_cast(u32, e);
    }
    ((uint4*)kk)[i] = kv;
}

// ---------------- f16 MFMA GEMM: C[M,N] = A[M,K] (ldA) * B^T (B=[N][K], pitch K) ----------
// EPI bits: 1=+bias[n](f32)  2=leaky(0.2)  4=+Cres(f32)  8=write Cf(f32)
//           16=write Ch(f16 row-major)  32=write Ch transposed [b][n][m]
//           64=fused QKV: bn<256 -> Ch(Q), <512 -> Ch2(K), else Ch3(V transposed)
// tile BM x BN x 32, 256 threads = 4 waves (2x2), per-wave (BM/2)x(BN/2)
template<int EPI, int BM, int BN>
__global__ __launch_bounds__(256)
void gemm_mfma(const u16* __restrict__ A, const u16* __restrict__ B,
               const float* __restrict__ bias, const float* __restrict__ Cres,
               float* __restrict__ Cf, u16* __restrict__ Ch,
               u16* __restrict__ Ch2, u16* __restrict__ Ch3,
               int M, int N, int K, int ldA,
               long sA, long sB, long sC)
{
    constexpr int FM = BM / 32, FN = BN / 32;
    __shared__ u16 As[BM * 32];
    __shared__ u16 Bs[BN * 32];
    const int bz = blockIdx.z;
    A += (long)bz * sA;
    B += (long)bz * sB;
    if constexpr (EPI & 4)  Cres += (long)bz * sC;
    if constexpr (EPI & 8)  Cf   += (long)bz * sC;
    if constexpr ((EPI & 16) && !(EPI & (32 | 64))) Ch += (long)bz * sC;
    const int bm = blockIdx.y * BM;
    const int bn = blockIdx.x * BN;
    const int t = threadIdx.x;
    const int lane = t & 63, wave = t >> 6;
    const int wm = (wave >> 1) * (BM / 2), wn = (wave & 1) * (BN / 2);

    f32x4 acc[FM][FN];
    #pragma unroll
    for (int i = 0; i < FM; ++i)
        #pragma unroll
        for (int j = 0; j < FN; ++j)
            acc[i][j] = (f32x4){0.f, 0.f, 0.f, 0.f};

    const u16* gA0 = A + (long)(bm + (t >> 2)) * ldA + (t & 3) * 8;
    const u16* gB0 = B + (long)(bn + (t >> 2)) * K + (t & 3) * 8;
    u16* lA0 = As + wave * 512;          // wave-uniform LDS bases
    u16* lB0 = Bs + wave * 512;

    const int arow = wm + (lane & 15);
    const int brow = wn + (lane & 15);
    const int ko = (lane >> 4) * 8;

    for (int k0 = 0; k0 < K; k0 += 32) {
        __syncthreads();                 // previous tile fully consumed
        gl16(gA0, lA0);
        if constexpr (BM == 128) gl16(gA0 + 64L * ldA, As + 2048 + wave * 512);
        gl16(gB0, lB0);
        if constexpr (BN == 128) gl16(gB0 + 64L * K, Bs + 2048 + wave * 512);
        gA0 += 32; gB0 += 32;
        __syncthreads();                 // implies vmcnt(0): tile ready
        h8 af[FM], bf[FN];
        #pragma unroll
        for (int i = 0; i < FM; ++i) af[i] = *(const h8*)&As[(arow + i * 16) * 32 + ko];
        #pragma unroll
        for (int j = 0; j < FN; ++j) bf[j] = *(const h8*)&Bs[(brow + j * 16) * 32 + ko];
        #pragma unroll
        for (int i = 0; i < FM; ++i)
            #pragma unroll
            for (int j = 0; j < FN; ++j)
                acc[i][j] = __builtin_amdgcn_mfma_f32_16x16x32_f16(af[i], bf[j], acc[i][j], 0, 0, 0);
    }

    // epilogue: C/D layout col=lane&15, row=(lane>>4)*4+reg
    const int colc = lane & 15;
    const int rowb = (lane >> 4) * 4;
    if constexpr (EPI & 64) {
        const int seg = bn >> 8;          // 0=Q,1=K,2=V
        const int nb  = bn & 255;
        if (seg < 2) {
            u16* dst = seg ? Ch2 : Ch;
            #pragma unroll
            for (int i = 0; i < FM; ++i)
                #pragma unroll
                for (int j = 0; j < FN; ++j) {
                    int nn = nb + wn + j * 16 + colc;
                    #pragma unroll
                    for (int r = 0; r < 4; ++r) {
                        long row = bm + wm + i * 16 + rowb + r;
                        dst[row * DD + nn] = f2h(acc[i][j][r]);
                    }
                }
        } else {
            #pragma unroll
            for (int i = 0; i < FM; ++i) {
                int r0 = bm + wm + i * 16 + rowb;
                int b  = r0 >> 11;
                int m0 = r0 & (LL - 1);
                #pragma unroll
                for (int j = 0; j < FN; ++j) {
                    int nn = nb + wn + j * 16 + colc;
                    f32x4 v = acc[i][j];
                    ushort4 pk;
                    pk.x = f2h(v.x); pk.y = f2h(v.y); pk.z = f2h(v.z); pk.w = f2h(v.w);
                    *(ushort4*)&Ch3[((long)b * DD + nn) * LL + m0] = pk;
                }
            }
        }
    } else if constexpr (EPI & 32) {
        #pragma unroll
        for (int i = 0; i < FM; ++i) {
            int r0 = bm + wm + i * 16 + rowb;
            int b  = r0 >> 11;
            int m0 = r0 & (LL - 1);
            #pragma unroll
            for (int j = 0; j < FN; ++j) {
                int n = bn + wn + j * 16 + colc;
                f32x4 v = acc[i][j];
                ushort4 pk;
                pk.x = f2h(v.x); pk.y = f2h(v.y); pk.z = f2h(v.z); pk.w = f2h(v.w);
                *(ushort4*)&Ch[((long)b * DD + n) * LL + m0] = pk;
            }
        }
    } else {
        #pragma unroll
        for (int i = 0; i < FM; ++i) {
            #pragma unroll
            for (int j = 0; j < FN; ++j) {
                int n = bn + wn + j * 16 + colc;
                float bv = (EPI & 1) ? bias[n] : 0.f;
                #pragma unroll
                for (int r = 0; r < 4; ++r) {
                    long row = bm + wm + i * 16 + rowb + r;
                    float val = acc[i][j][r] + bv;
                    if (EPI & 2) val = (val >= 0.f) ? val : 0.2f * val;
                    long off = row * (long)N + n;
                    if (EPI & 4) val += Cres[off];
                    if (EPI & 8) Cf[off] = val;
                    if (EPI & 16) Ch[off] = f2h(val);
                }
            }
        }
    }
}

// ---------------- skew + scale + softmax; f16 in, f16 probs in place --------
// scores[b,i,m] = (S1[b,i,m] + Srel)/8 ; Srel = QE[i, m-i+L-1] (m<=i), 0 (m==i+1),
//                 QE[i+1, m-i-2] (m>=i+2)
__global__ __launch_bounds__(256)
void skew_softmax(u16* __restrict__ S1, const u16* __restrict__ QE)
{
    const int bi = blockIdx.x;
    const int b = bi >> 11;
    const int i = bi & (LL - 1);
    u16* srow = S1 + (long)bi * LL;
    const u16* qe_i  = QE + ((long)b * LL + i) * LL;
    const u16* qe_i1 = qe_i + ((i + 1 < LL) ? LL : 0);
    const int t = threadIdx.x;

    uint4 sv = ((const uint4*)srow)[t];      // elements m = t*8 .. t*8+7
    const u16* se = (const u16*)&sv;
    float vals[8];
    float mx = -1e30f;
    #pragma unroll
    for (int j = 0; j < 8; ++j) {
        int m = t * 8 + j;
        float srel;
        if (m <= i)            srel = h2f(qe_i[m - i + (LL - 1)]);
        else if (m == i + 1)   srel = 0.f;
        else                   srel = h2f(qe_i1[m - i - 2]);
        float s = (h2f(se[j]) + srel) * 0.125f;
        vals[j] = s;
        mx = fmaxf(mx, s);
    }
    #pragma unroll
    for (int off = 32; off >= 1; off >>= 1)
        mx = fmaxf(mx, __shfl_xor(mx, off, 64));
    __shared__ float redm[4], reds[4];
    const int wid = t >> 6;
    if ((t & 63) == 0) redm[wid] = mx;
    __syncthreads();
    mx = fmaxf(fmaxf(redm[0], redm[1]), fmaxf(redm[2], redm[3]));

    float sum = 0.f;
    #pragma unroll
    for (int j = 0; j < 8; ++j) { vals[j] = expf(vals[j] - mx); sum += vals[j]; }
    #pragma unroll
    for (int off = 32; off >= 1; off >>= 1)
        sum += __shfl_xor(sum, off, 64);
    if ((t & 63) == 0) reds[wid] = sum;
    __syncthreads();
    sum = reds[0] + reds[1] + reds[2] + reds[3];
    float inv = 1.0f / sum;
    uint4 ov;
    u16* oe = (u16*)&ov;
    #pragma unroll
    for (int j = 0; j < 8; ++j) oe[j] = f2h(vals[j] * inv);
    ((uint4*)srow)[t] = ov;
}

// ---------------- final classifier ----------------
__global__ __launch_bounds__(960)
void fc_partial(const float* __restrict__ x, const float* __restrict__ W,
                float* __restrict__ part)
{
    const int v = threadIdx.x;
    const int b = threadIdx.y;
    const int chunk = blockIdx.x;
    const int KC = (int)(LD_ / 256);
    const long k0 = (long)chunk * KC;
    const float* xb = x + (long)b * LD_ + k0;
    const float* Wp = W + k0 * VV + v;
    float acc = 0.f;
    #pragma unroll 4
    for (int k2 = 0; k2 < KC; ++k2)
        acc = fmaf(xb[k2], Wp[(long)k2 * VV], acc);
    part[((long)chunk * BB + b) * VV + v] = acc;
}

__global__ __launch_bounds__(960)
void fc_finish(const float* __restrict__ part, const float* __restrict__ bias,
               float* __restrict__ out)
{
    const int v = threadIdx.x, b = threadIdx.y;
    float acc = bias[v];
    for (int c = 0; c < 256; ++c)
        acc += part[((long)c * BB + b) * VV + v];
    __shared__ float lds[BB][VV];
    __shared__ float mxs[BB], sms[BB];
    lds[b][v] = acc;
    __syncthreads();
    if (v == 0) {
        float m = -1e30f;
        for (int j = 0; j < VV; ++j) m = fmaxf(m, lds[b][j]);
        float s = 0.f;
        for (int j = 0; j < VV; ++j) s += expf(lds[b][j] - m);
        mxs[b] = m; sms[b] = s;
    }
    __syncthreads();
    out[b * VV + v] = expf(lds[b][v] - mxs[b]) / sms[b];
}

// ---------------- driver ----------------
extern "C" void kernel_launch(void* const* d_in, const int* in_sizes, int n_in,
                              void* d_out, int out_size, void* d_ws, size_t ws_size,
                              hipStream_t stream)
{
    const int*   tokens = (const int*)d_in[0];
    const float* table  = (const float*)d_in[1];
    const float* Wq1 = (const float*)d_in[2];
    const float* Wk1 = (const float*)d_in[3];
    const float* Wv1 = (const float*)d_in[4];
    const float* Wq2 = (const float*)d_in[5];
    const float* Wk2 = (const float*)d_in[6];
    const float* Wv2 = (const float*)d_in[7];
    const float* Wf1 = (const float*)d_in[8];
    const float* bf1 = (const float*)d_in[9];
    const float* Wf2 = (const float*)d_in[10];
    const float* bf2 = (const float*)d_in[11];
    const float* Wfc = (const float*)d_in[12];
    const float* bfc = (const float*)d_in[13];

    char* p = (char*)d_ws;
    float* x  = (float*)p; p += BLD * 4;
    u16* xh = (u16*)p;     p += BLD * 2;
    u16* qb = (u16*)p;     p += BLD * 2;
    u16* kb = (u16*)p;     p += BLD * 2;
    u16* vt = (u16*)p;     p += BLD * 2;        // [B][D][L]
    u16* S1 = (u16*)p;     p += BLL * 2;        // f16 scores -> probs in place
    u16* QE = (u16*)p;     p += BLL * 2;
    u16* qkvw = (u16*)p;   p += 12L * 3 * 65536 * 2;  // [(h*6+l)][3][256][256]
    u16* fw = (u16*)p;     p += 12L * 65536 * 2;      // [f1:6][f2:6][256][256]
    float* part = (float*)p;
    u16* hb = qb;                               // FFN hidden aliases Q buffer

    // weight conversion: qkv interleaved per (half,layer), layer stride 3*65536
    wconv<<<384, 256, 0, stream>>>(Wq1, qkvw + 0L * 65536,            3 * 65536);
    wconv<<<384, 256, 0, stream>>>(Wk1, qkvw + 1L * 65536,            3 * 65536);
    wconv<<<384, 256, 0, stream>>>(Wv1, qkvw + 2L * 65536,            3 * 65536);
    wconv<<<384, 256, 0, stream>>>(Wq2, qkvw + 18L * 65536,           3 * 65536);
    wconv<<<384, 256, 0, stream>>>(Wk2, qkvw + 18L * 65536 + 65536,   3 * 65536);
    wconv<<<384, 256, 0, stream>>>(Wv2, qkvw + 18L * 65536 + 2 * 65536, 3 * 65536);
    wconv<<<384, 256, 0, stream>>>(Wf1, fw, 65536);
    wconv<<<384, 256, 0, stream>>>(Wf2, fw + 6L * 65536, 65536);

    embed_kernel<<<(int)((BLD + 255) / 256), 256, 0, stream>>>(tokens, table, x, xh);

    const dim3 gqkv(6, 64, 1);        // 8192 x 768, 128-tiles
    const dim3 gscore(16, 16, BB);    // 2048 x 2048, 128-tiles
    const dim3 gpv(4, 32, BB);        // 2048 x 256, 64-tiles
    const dim3 gffn(4, 128, 1);       // 8192 x 256, 64-tiles

    for (int layer = 0; layer < NLAYERS; ++layer) {
        for (int half = 0; half < 2; ++half) {
            const u16* wqkv = qkvw + ((long)(half * 6 + layer)) * 3 * 65536;
            // fused QKV projection: Q,K row-major; V transposed
            gemm_mfma<64, 128, 128><<<gqkv, 256, 0, stream>>>(
                xh, wqkv, nullptr, nullptr, nullptr, qb, kb, vt,
                BB * LL, 768, DD, DD, 0, 0, 0);
            // S1 = Q K^T (f16 out)
            gemm_mfma<16, 128, 128><<<gscore, 256, 0, stream>>>(
                qb, kb, nullptr, nullptr, nullptr, S1, nullptr, nullptr,
                LL, LL, DD, DD, LD_, LD_, LxL);
            // E = K - Q
            sub_f16<<<(int)(BLD / 8 / 256), 256, 0, stream>>>(kb, qb);
            // QE = Q E^T (f16 out)
            gemm_mfma<16, 128, 128><<<gscore, 256, 0, stream>>>(
                qb, kb, nullptr, nullptr, nullptr, QE, nullptr, nullptr,
                LL, LL, DD, DD, LD_, LD_, LxL);
            // probs = softmax((S1 + skew(QE))/8) in place
            skew_softmax<<<BB * LL, 256, 0, stream>>>(S1, QE);
            // x = probs @ V + x
            gemm_mfma<4 | 8 | 16, 64, 64><<<gpv, 256, 0, stream>>>(
                S1, vt, nullptr, x, x, xh, nullptr, nullptr,
                LL, DD, LL, LL, LxL, LD_, LD_);
        }
        // FFN
        gemm_mfma<1 | 2 | 16, 64, 64><<<gffn, 256, 0, stream>>>(
            xh, fw + (long)layer * 65536, bf1 + layer * DD, nullptr,
            nullptr, hb, nullptr, nullptr, BB * LL, DD, DD, DD, 0, 0, 0);
        gemm_mfma<1 | 8 | 16, 64, 64><<<gffn, 256, 0, stream>>>(
            hb, fw + (long)(6 + layer) * 65536, bf2 + layer * DD, nullptr,
            x, xh, nullptr, nullptr, BB * LL, DD, DD, DD, 0, 0, 0);
    }

    fc_partial<<<256, dim3(VV, BB, 1), 0, stream>>>(x, Wfc, part);
    fc_finish<<<1, dim3(VV, BB, 1), 0, stream>>>(part, bfc, (float*)d_out);
}

// Round 5
// 1783.153 us; speedup vs baseline: 4.3768x; 1.0721x over previous
//
#include <hip/hip_runtime.h>
#include <hip/hip_fp16.h>

typedef unsigned short u16;
typedef unsigned int   u32;

#define BB 4
#define LL 2048
#define DD 256
#define VV 240
#define NLAYERS 6

static constexpr long BLD = (long)BB * LL * DD;   // 2,097,152
static constexpr long LD_ = (long)LL * DD;        // 524,288
static constexpr long LxL = (long)LL * LL;        // 4,194,304
static constexpr long BLL = (long)BB * LxL;       // 16,777,216

typedef _Float16 h8  __attribute__((ext_vector_type(8)));   // MFMA A/B fragment
typedef float  f32x4 __attribute__((ext_vector_type(4)));

__device__ __forceinline__ u16 f2h(float f) {
    _Float16 h = (_Float16)f;
    return __builtin_bit_cast(u16, h);
}
__device__ __forceinline__ float h2f(u16 u) {
    return (float)__builtin_bit_cast(_Float16, u);
}

__device__ __forceinline__ void gl16(const void* g, void* l) {
    __builtin_amdgcn_global_load_lds((const __attribute__((address_space(1))) void*)g,
                                     (__attribute__((address_space(3))) void*)l, 16, 0, 0);
}

// ---------------- embedding + positional encoding ----------------
__global__ __launch_bounds__(256)
void embed_kernel(const int* __restrict__ tokens, const float* __restrict__ table,
                  float* __restrict__ x, u16* __restrict__ xh)
{
    long idx = (long)blockIdx.x * 256 + threadIdx.x;
    if (idx >= BLD) return;
    int i  = (int)(idx & (DD - 1));
    long bl = idx >> 8;
    int l  = (int)(bl & (LL - 1));
    int tok = tokens[bl];
    float base = (float)l * 1e-5f;
    float p = powf(base, (float)i * (1.0f / (float)DD));
    float ang = p - ((i & 1) ? 0.0f : 1.57079632679489662f);
    float v = table[(long)tok * DD + i] + sinf(ang);
    x[idx] = v;
    xh[idx] = f2h(v);
}

// ------ weight convert+transpose: dst[m*lstride + n*256 + k] = f16(W[m][k][n] - Wsub[m][k][n]) --
template<bool DIFF>
__global__ __launch_bounds__(256)
void wconv(const float* __restrict__ W, const float* __restrict__ Wsub,
           u16* __restrict__ Wt, long lstride)
{
    int blk = blockIdx.x;            // 6 layers * 64 tiles
    int m  = blk >> 6;
    int ti = (blk >> 3) & 7;         // k tile
    int tj = blk & 7;                // n tile
    const float* src = W + (long)m * 65536;
    u16* dst = Wt + (long)m * lstride;
    __shared__ float tile[32][33];
    int t = threadIdx.x;
    int c = t & 31, r8 = t >> 5;
    #pragma unroll
    for (int p = 0; p < 4; ++p) {
        int r = r8 + p * 8;
        long off = (long)(ti * 32 + r) * 256 + tj * 32 + c;
        float v = src[off];
        if constexpr (DIFF) v -= Wsub[(long)m * 65536 + off];
        tile[r][c] = v;
    }
    __syncthreads();
    #pragma unroll
    for (int p = 0; p < 4; ++p) {
        int n = r8 + p * 8;
        dst[(long)(tj * 32 + n) * 256 + ti * 32 + c] = f2h(tile[c][n]);
    }
}

// ---------------- f16 MFMA GEMM, 2-phase double-buffered pipeline ----------------
// C[M,N] = A[M,K] (row pitch ldA) * B^T  (B stored [N][K], pitch K)
// EPI bits: 1=+bias[n](f32)  2=leaky(0.2)  4=+Cres(f32)  8=write Cf(f32)  16=write Ch(f16)
//   64 = QKEV quad-output: col seg 0->Ch(Q), 1->Ch2(K), 2->Ch3(E), 3->Ch4(V transposed [b][d][l])
//  128 = dual score: bn<2048 uses B  -> Ch(S1);  bn>=2048 uses B2 -> Ch2(QE); pitch LL
template<int EPI, int BM, int BN>
__global__ __launch_bounds__(256)
void gemm_mfma(const u16* __restrict__ A, const u16* __restrict__ B,
               const u16* __restrict__ B2,
               const float* __restrict__ bias, const float* __restrict__ Cres,
               float* __restrict__ Cf, u16* __restrict__ Ch,
               u16* __restrict__ Ch2, u16* __restrict__ Ch3, u16* __restrict__ Ch4,
               int M, int N, int K, int ldA,
               long sA, long sB, long sC)
{
    constexpr int FM = BM / 32, FN = BN / 32;
    __shared__ u16 As[2][BM * 32];
    __shared__ u16 Bs[2][BN * 32];
    const int bz = blockIdx.z;
    A += (long)bz * sA;
    const int bm = blockIdx.y * BM;
    const int bn = blockIdx.x * BN;
    int bnb = bn;                    // column index for B addressing
    const u16* Bp;
    if constexpr (EPI & 128) {
        Bp = (bn >= LL) ? B2 : B;
        if (bn >= LL) bnb = bn - LL;
        Bp += (long)bz * sB;
    } else {
        Bp = B + (long)bz * sB;
    }
    if constexpr (EPI & 4)  Cres += (long)bz * sC;
    if constexpr (EPI & 8)  Cf   += (long)bz * sC;
    if constexpr ((EPI & 16) && !(EPI & (64 | 128))) Ch += (long)bz * sC;

    const int t = threadIdx.x;
    const int lane = t & 63, wave = t >> 6;
    const int wm = (wave >> 1) * (BM / 2), wn = (wave & 1) * (BN / 2);

    f32x4 acc[FM][FN];
    #pragma unroll
    for (int i = 0; i < FM; ++i)
        #pragma unroll
        for (int j = 0; j < FN; ++j)
            acc[i][j] = (f32x4){0.f, 0.f, 0.f, 0.f};

    const u16* gA0 = A  + (long)(bm  + (t >> 2)) * ldA + (t & 3) * 8;
    const u16* gB0 = Bp + (long)(bnb + (t >> 2)) * K   + (t & 3) * 8;

    const int arow = wm + (lane & 15);
    const int brow = wn + (lane & 15);
    const int ko = (lane >> 4) * 8;

    #define STAGE(buf, koff) do {                                              \
        gl16(gA0 + (koff), &As[buf][wave * 512]);                              \
        if constexpr (BM == 128) gl16(gA0 + 64L * ldA + (koff),                \
                                      &As[buf][2048 + wave * 512]);            \
        gl16(gB0 + (koff), &Bs[buf][wave * 512]);                              \
        if constexpr (BN == 128) gl16(gB0 + 64L * K + (koff),                  \
                                      &Bs[buf][2048 + wave * 512]);            \
    } while (0)

    STAGE(0, 0);
    int cur = 0;
    for (int k0 = 0; k0 < K; k0 += 32) {
        __syncthreads();                       // drains vmcnt -> buf[cur] ready
        if (k0 + 32 < K) {                     // issue next tile early: latency
            if (cur) STAGE(0, k0 + 32);        //   hides under this tile's MFMA
            else     STAGE(1, k0 + 32);
        }
        h8 af[FM], bf[FN];
        #pragma unroll
        for (int i = 0; i < FM; ++i) af[i] = *(const h8*)&As[cur][(arow + i * 16) * 32 + ko];
        #pragma unroll
        for (int j = 0; j < FN; ++j) bf[j] = *(const h8*)&Bs[cur][(brow + j * 16) * 32 + ko];
        #pragma unroll
        for (int i = 0; i < FM; ++i)
            #pragma unroll
            for (int j = 0; j < FN; ++j)
                acc[i][j] = __builtin_amdgcn_mfma_f32_16x16x32_f16(af[i], bf[j], acc[i][j], 0, 0, 0);
        cur ^= 1;
    }
    #undef STAGE

    // epilogue: C/D layout col=lane&15, row=(lane>>4)*4+reg
    const int colc = lane & 15;
    const int rowb = (lane >> 4) * 4;
    if constexpr (EPI & 64) {
        const int seg = bn >> 8;          // 0=Q,1=K,2=E,3=V^T
        const int nb  = bn & 255;
        if (seg < 3) {
            u16* dst = (seg == 0) ? Ch : ((seg == 1) ? Ch2 : Ch3);
            #pragma unroll
            for (int i = 0; i < FM; ++i)
                #pragma unroll
                for (int j = 0; j < FN; ++j) {
                    int nn = nb + wn + j * 16 + colc;
                    #pragma unroll
                    for (int r = 0; r < 4; ++r) {
                        long row = bm + wm + i * 16 + rowb + r;
                        dst[row * DD + nn] = f2h(acc[i][j][r]);
                    }
                }
        } else {
            #pragma unroll
            for (int i = 0; i < FM; ++i) {
                int r0 = bm + wm + i * 16 + rowb;
                int b  = r0 >> 11;
                int m0 = r0 & (LL - 1);
                #pragma unroll
                for (int j = 0; j < FN; ++j) {
                    int nn = nb + wn + j * 16 + colc;
                    f32x4 v = acc[i][j];
                    ushort4 pk;
                    pk.x = f2h(v.x); pk.y = f2h(v.y); pk.z = f2h(v.z); pk.w = f2h(v.w);
                    *(ushort4*)&Ch4[((long)b * DD + nn) * LL + m0] = pk;
                }
            }
        }
    } else if constexpr (EPI & 128) {
        u16* dst = ((bn >= LL) ? Ch2 : Ch) + (long)bz * sC;
        const int nb = bn & (LL - 1);
        #pragma unroll
        for (int i = 0; i < FM; ++i)
            #pragma unroll
            for (int j = 0; j < FN; ++j) {
                int n = nb + wn + j * 16 + colc;
                #pragma unroll
                for (int r = 0; r < 4; ++r) {
                    long row = bm + wm + i * 16 + rowb + r;
                    dst[row * LL + n] = f2h(acc[i][j][r]);
                }
            }
    } else {
        #pragma unroll
        for (int i = 0; i < FM; ++i) {
            #pragma unroll
            for (int j = 0; j < FN; ++j) {
                int n = bn + wn + j * 16 + colc;
                float bv = (EPI & 1) ? bias[n] : 0.f;
                #pragma unroll
                for (int r = 0; r < 4; ++r) {
                    long row = bm + wm + i * 16 + rowb + r;
                    float val = acc[i][j][r] + bv;
                    if (EPI & 2) val = (val >= 0.f) ? val : 0.2f * val;
                    long off = row * (long)N + n;
                    if (EPI & 4) val += Cres[off];
                    if (EPI & 8) Cf[off] = val;
                    if (EPI & 16) Ch[off] = f2h(val);
                }
            }
        }
    }
}

// ---------------- skew + scale + softmax; f16 in, f16 probs in place --------
__global__ __launch_bounds__(256)
void skew_softmax(u16* __restrict__ S1, const u16* __restrict__ QE)
{
    const int bi = blockIdx.x;
    const int b = bi >> 11;
    const int i = bi & (LL - 1);
    u16* srow = S1 + (long)bi * LL;
    const u16* qe_i  = QE + ((long)b * LL + i) * LL;
    const u16* qe_i1 = qe_i + ((i + 1 < LL) ? LL : 0);
    const int t = threadIdx.x;

    uint4 sv = ((const uint4*)srow)[t];      // elements m = t*8 .. t*8+7
    const u16* se = (const u16*)&sv;
    float vals[8];
    float mx = -1e30f;
    #pragma unroll
    for (int j = 0; j < 8; ++j) {
        int m = t * 8 + j;
        float srel;
        if (m <= i)            srel = h2f(qe_i[m - i + (LL - 1)]);
        else if (m == i + 1)   srel = 0.f;
        else                   srel = h2f(qe_i1[m - i - 2]);
        float s = (h2f(se[j]) + srel) * 0.125f;
        vals[j] = s;
        mx = fmaxf(mx, s);
    }
    #pragma unroll
    for (int off = 32; off >= 1; off >>= 1)
        mx = fmaxf(mx, __shfl_xor(mx, off, 64));
    __shared__ float redm[4], reds[4];
    const int wid = t >> 6;
    if ((t & 63) == 0) redm[wid] = mx;
    __syncthreads();
    mx = fmaxf(fmaxf(redm[0], redm[1]), fmaxf(redm[2], redm[3]));

    float sum = 0.f;
    #pragma unroll
    for (int j = 0; j < 8; ++j) { vals[j] = expf(vals[j] - mx); sum += vals[j]; }
    #pragma unroll
    for (int off = 32; off >= 1; off >>= 1)
        sum += __shfl_xor(sum, off, 64);
    if ((t & 63) == 0) reds[wid] = sum;
    __syncthreads();
    sum = reds[0] + reds[1] + reds[2] + reds[3];
    float inv = 1.0f / sum;
    uint4 ov;
    u16* oe = (u16*)&ov;
    #pragma unroll
    for (int j = 0; j < 8; ++j) oe[j] = f2h(vals[j] * inv);
    ((uint4*)srow)[t] = ov;
}

// ---------------- final classifier ----------------
__global__ __launch_bounds__(960)
void fc_partial(const float* __restrict__ x, const float* __restrict__ W,
                float* __restrict__ part)
{
    const int v = threadIdx.x;
    const int b = threadIdx.y;
    const int chunk = blockIdx.x;
    const int KC = (int)(LD_ / 256);
    const long k0 = (long)chunk * KC;
    const float* xb = x + (long)b * LD_ + k0;
    const float* Wp = W + k0 * VV + v;
    float acc = 0.f;
    #pragma unroll 4
    for (int k2 = 0; k2 < KC; ++k2)
        acc = fmaf(xb[k2], Wp[(long)k2 * VV], acc);
    part[((long)chunk * BB + b) * VV + v] = acc;
}

__global__ __launch_bounds__(960)
void fc_finish(const float* __restrict__ part, const float* __restrict__ bias,
               float* __restrict__ out)
{
    const int v = threadIdx.x, b = threadIdx.y;
    float acc = bias[v];
    for (int c = 0; c < 256; ++c)
        acc += part[((long)c * BB + b) * VV + v];
    __shared__ float lds[BB][VV];
    __shared__ float mxs[BB], sms[BB];
    lds[b][v] = acc;
    __syncthreads();
    if (v == 0) {
        float m = -1e30f;
        for (int j = 0; j < VV; ++j) m = fmaxf(m, lds[b][j]);
        float s = 0.f;
        for (int j = 0; j < VV; ++j) s += expf(lds[b][j] - m);
        mxs[b] = m; sms[b] = s;
    }
    __syncthreads();
    out[b * VV + v] = expf(lds[b][v] - mxs[b]) / sms[b];
}

// ---------------- driver ----------------
extern "C" void kernel_launch(void* const* d_in, const int* in_sizes, int n_in,
                              void* d_out, int out_size, void* d_ws, size_t ws_size,
                              hipStream_t stream)
{
    const int*   tokens = (const int*)d_in[0];
    const float* table  = (const float*)d_in[1];
    const float* Wq1 = (const float*)d_in[2];
    const float* Wk1 = (const float*)d_in[3];
    const float* Wv1 = (const float*)d_in[4];
    const float* Wq2 = (const float*)d_in[5];
    const float* Wk2 = (const float*)d_in[6];
    const float* Wv2 = (const float*)d_in[7];
    const float* Wf1 = (const float*)d_in[8];
    const float* bf1 = (const float*)d_in[9];
    const float* Wf2 = (const float*)d_in[10];
    const float* bf2 = (const float*)d_in[11];
    const float* Wfc = (const float*)d_in[12];
    const float* bfc = (const float*)d_in[13];

    char* p = (char*)d_ws;
    float* x  = (float*)p; p += BLD * 4;
    u16* xh = (u16*)p;     p += BLD * 2;
    u16* qb = (u16*)p;     p += BLD * 2;
    u16* kb = (u16*)p;     p += BLD * 2;
    u16* eb = (u16*)p;     p += BLD * 2;        // E = K - Q
    u16* vt = (u16*)p;     p += BLD * 2;        // [B][D][L]
    u16* S1 = (u16*)p;     p += BLL * 2;        // f16 scores -> probs in place
    u16* QE = (u16*)p;     p += BLL * 2;
    u16* qkevw = (u16*)p;  p += 12L * 4 * 65536 * 2;  // [(h*6+l)][4][256][256] (Q,K,E,V)
    u16* fw = (u16*)p;     p += 12L * 65536 * 2;      // [f1:6][f2:6][256][256]
    float* part = (float*)p;
    u16* hb = qb;                               // FFN hidden aliases Q buffer

    // weight conversion: QKEV interleaved per (half,layer), layer stride 4*65536
    const long LS = 4 * 65536;
    wconv<false><<<384, 256, 0, stream>>>(Wq1, nullptr, qkevw + 0L * 65536, LS);
    wconv<false><<<384, 256, 0, stream>>>(Wk1, nullptr, qkevw + 1L * 65536, LS);
    wconv<true ><<<384, 256, 0, stream>>>(Wk1, Wq1,     qkevw + 2L * 65536, LS);
    wconv<false><<<384, 256, 0, stream>>>(Wv1, nullptr, qkevw + 3L * 65536, LS);
    wconv<false><<<384, 256, 0, stream>>>(Wq2, nullptr, qkevw + 24L * 65536, LS);
    wconv<true ><<<384, 256, 0, stream>>>(Wk2, Wq2,     qkevw + 24L * 65536 + 2 * 65536, LS);
    wconv<false><<<384, 256, 0, stream>>>(Wk2, nullptr, qkevw + 24L * 65536 + 1 * 65536, LS);
    wconv<false><<<384, 256, 0, stream>>>(Wv2, nullptr, qkevw + 24L * 65536 + 3 * 65536, LS);
    wconv<false><<<384, 256, 0, stream>>>(Wf1, nullptr, fw, 65536);
    wconv<false><<<384, 256, 0, stream>>>(Wf2, nullptr, fw + 6L * 65536, 65536);

    embed_kernel<<<(int)((BLD + 255) / 256), 256, 0, stream>>>(tokens, table, x, xh);

    const dim3 gqkev(8, 64, 1);       // 8192 x 1024, 128-tiles
    const dim3 gscore(32, 16, BB);    // 2048 x 4096(dual), 128-tiles
    const dim3 gpv(4, 32, BB);        // 2048 x 256, 64-tiles
    const dim3 gffn(4, 128, 1);       // 8192 x 256, 64-tiles

    for (int layer = 0; layer < NLAYERS; ++layer) {
        for (int half = 0; half < 2; ++half) {
            const u16* wqkev = qkevw + ((long)(half * 6 + layer)) * LS;
            // fused QKEV projection: Q,K,E row-major; V transposed
            gemm_mfma<64, 128, 128><<<gqkev, 256, 0, stream>>>(
                xh, wqkev, nullptr, nullptr, nullptr, nullptr, qb, kb, eb, vt,
                BB * LL, 1024, DD, DD, 0, 0, 0);
            // S1 = Q K^T and QE = Q E^T in one dispatch (f16 out)
            gemm_mfma<128, 128, 128><<<gscore, 256, 0, stream>>>(
                qb, kb, eb, nullptr, nullptr, nullptr, S1, QE, nullptr, nullptr,
                LL, LL, DD, DD, LD_, LD_, LxL);
            // probs = softmax((S1 + skew(QE))/8) in place
            skew_softmax<<<BB * LL, 256, 0, stream>>>(S1, QE);
            // x = probs @ V + x
            gemm_mfma<4 | 8 | 16, 64, 64><<<gpv, 256, 0, stream>>>(
                S1, vt, nullptr, nullptr, x, x, xh, nullptr, nullptr, nullptr,
                LL, DD, LL, LL, LxL, LD_, LD_);
        }
        // FFN
        gemm_mfma<1 | 2 | 16, 64, 64><<<gffn, 256, 0, stream>>>(
            xh, fw + (long)layer * 65536, nullptr, bf1 + layer * DD, nullptr,
            nullptr, hb, nullptr, nullptr, nullptr, BB * LL, DD, DD, DD, 0, 0, 0);
        gemm_mfma<1 | 8 | 16, 64, 64><<<gffn, 256, 0, stream>>>(
            hb, fw + (long)(6 + layer) * 65536, nullptr, bf2 + layer * DD, nullptr,
            x, xh, nullptr, nullptr, nullptr, BB * LL, DD, DD, DD, 0, 0, 0);
    }

    fc_partial<<<256, dim3(VV, BB, 1), 0, stream>>>(x, Wfc, part);
    fc_finish<<<1, dim3(VV, BB, 1), 0, stream>>>(part, bfc, (float*)d_out);
}